// Round 11
// baseline (214.819 us; speedup 1.0000x reference)
//
#include <hip/hip_runtime.h>
#include <hip/hip_fp8.h>

#define LOGZERO -4290774016.0f   // -(65504^2), exactly representable in fp32
#define L2E 1.4426950408889634f  // log2(e)
#define LN2 0.6931471805599453f

constexpr int Bb = 32, Tt = 512, Dd = 512, Vv = 4096;
constexpr int BT = Bb * Tt;

typedef __attribute__((ext_vector_type(4)))  float f32x4;
typedef __attribute__((ext_vector_type(16))) float f32x16;
typedef __attribute__((ext_vector_type(4)))  int   i32x4;
typedef __attribute__((ext_vector_type(8)))  int   i32x8;

#define GLOBAL_AS __attribute__((address_space(1)))
#define LDS_AS    __attribute__((address_space(3)))

__device__ __forceinline__ float fexp2(float x) { return __builtin_amdgcn_exp2f(x); }  // 2^x
__device__ __forceinline__ float flog2(float x) { return __builtin_amdgcn_logf(x); }   // log2(x)

// pack 4 floats (scaled) -> 4 OCP e4m3 bytes
__device__ __forceinline__ unsigned cvt4_fp8(float4 v, float s) {
#if __has_builtin(__builtin_amdgcn_cvt_pk_fp8_f32)
  int p = __builtin_amdgcn_cvt_pk_fp8_f32(v.x * s, v.y * s, 0, false);
  p = __builtin_amdgcn_cvt_pk_fp8_f32(v.z * s, v.w * s, p, true);
  return (unsigned)p;
#else
  unsigned b0 = __hip_cvt_float_to_fp8(v.x * s, __HIP_SATFINITE, __HIP_E4M3);
  unsigned b1 = __hip_cvt_float_to_fp8(v.y * s, __HIP_SATFINITE, __HIP_E4M3);
  unsigned b2 = __hip_cvt_float_to_fp8(v.z * s, __HIP_SATFINITE, __HIP_E4M3);
  unsigned b3 = __hip_cvt_float_to_fp8(v.w * s, __HIP_SATFINITE, __HIP_E4M3);
  return b0 | (b1 << 8) | (b2 << 16) | (b3 << 24);
#endif
}

// logaddexp in the log2 domain
__device__ __forceinline__ float lg2add(float a, float b) {
  float mx = fmaxf(a, b);
  float d  = fabsf(a - b);
  return mx + flog2(1.0f + fexp2(-d));
}

// load two b128 slots 1 KB apart and concat into an i32x8 MFMA operand
__device__ __forceinline__ i32x8 ld2(const unsigned char* p) {
  i32x4 lo = *(const i32x4*)p;
  i32x4 hx = *(const i32x4*)(p + 1024);
  return __builtin_shufflevector(lo, hx, 0, 1, 2, 3, 4, 5, 6, 7);
}

// ---- kPre v2: LDS-transposed coalesced pack into fp8 fragment layouts ----
// (unchanged — control). One block per 32-row output tile. Phase 1 reads
// contiguous 1-KB bursts/wave, converts, XOR-swizzled LDS store; phase 2
// gathers b128 fragment slots + 1-KB coalesced global stores.
// Xfp tile tM (16 KB): slot16 = (kb*2+h)*64 + khalf*32 + r
//   = fp8( x[tM*32+r][kb*64 + khalf*32 + h*16 + j] ), j=0..15
// Wp tile cb (32 KB): slot16 = (kb*4+ct*2+h)*64 + khalf*32 + r
//   = fp8( 16 * W[cb*64+ct*32+r][kb*64 + khalf*32 + h*16 + j] )
__global__ __launch_bounds__(256) void kPre(const float* __restrict__ x,
                                            const float* __restrict__ W,
                                            unsigned char* __restrict__ Xfp,
                                            unsigned char* __restrict__ Wp) {
  __shared__ unsigned char T[16384];
  const int tid = threadIdx.x, bid = blockIdx.x;
  const bool isX = bid < 512;
  const float* srcF;
  float scale;
  int cb = 0, half = 0;
  if (isX) {
    srcF = x + (size_t)bid * 32 * Dd;            // 32 contiguous rows
    scale = 1.0f;
  } else {
    int idx = bid - 512;                          // 0..127
    cb = idx >> 1; half = idx & 1;
    srcF = W + ((size_t)cb * 64 + half * 32) * Dd;
    scale = 16.0f;                                // x16 prescale (undone by MX scale_b)
  }

  // phase 1: fully-coalesced loads -> fp8 -> swizzled LDS
  #pragma unroll
  for (int p = 0; p < 16; ++p) {
    int f = p * 256 + tid;                        // float4 index 0..4095
    int r = f >> 7;                               // row 0..31
    int cf = f & 127;
    int c = cf >> 2, m = cf & 3;                  // 16-float chunk, float4 within
    float4 v = *(const float4*)(srcF + (size_t)f * 4);
    unsigned o = cvt4_fp8(v, scale);
    *(unsigned*)(T + ((r * 32 + (c ^ r)) * 16 + m * 4)) = o;
  }
  __syncthreads();

  // phase 2: gather fragment slots, 1-KB coalesced stores
  if (isX) {
    unsigned char* dst = Xfp + (size_t)bid * 16384;
    #pragma unroll
    for (int u = 0; u < 4; ++u) {
      int s = u * 256 + tid;                      // slot 0..1023
      int r = s & 31, khalf = (s >> 5) & 1, h = (s >> 6) & 1, kb = s >> 7;
      int c = kb * 4 + khalf * 2 + h;
      uint4 o = *(const uint4*)(T + (r * 32 + (c ^ r)) * 16);
      *(uint4*)(dst + (size_t)s * 16) = o;
    }
  } else {
    unsigned char* dst = Wp + (size_t)cb * 32768;
    #pragma unroll
    for (int u = 0; u < 4; ++u) {
      int lsl = u * 256 + tid;                    // local slot 0..1023 (ct=half)
      int r = lsl & 31, khalf = (lsl >> 5) & 1, h = (lsl >> 6) & 1, kb = lsl >> 7;
      int c = kb * 4 + khalf * 2 + h;
      int s = kb * 256 + half * 128 + h * 64 + khalf * 32 + r;
      uint4 o = *(const uint4*)(T + (r * 32 + (c ^ r)) * 16);
      *(uint4*)(dst + (size_t)s * 16) = o;
    }
  }
}

// ---- barrier-free MX-fp8 GEMM + exp-sum partials + beam scatter, M_tile=64 ----
// grid 4096, 256 threads (4 waves). R11 change: DEPTH-2 B prefetch.
// R10 analysis: kA 71 us, MfmaUtil 20% (14-us matrix floor), HBM 8%, nothing
// saturated -> K-loop latency exposure. Depth-1 prefetch covers ~400-cyc L2
// B-load latency with only ~270 cyc of MFMA+ds_read -> every kb iteration
// ends stalled on vmcnt. Depth-2 (3 B register stages, issue kb+2's loads
// each iteration) doubles the cover window. Registers: 64 AGPR acc + 48 B +
// ~45 addr/temps ~ 158 -> needs (256,3) cap 170 (occupancy 4->3 blocks/CU;
// R3-R5 showed block count is secondary once latency is covered).
// SPILL GUARD: WRITE_SIZE must stay ~11 MB.
// Epilogue: LDS-matrix row-sum (R8's 91.4->75.5 winner), scalarized scatter.
__global__ __launch_bounds__(256, 3) void kA(const unsigned char* __restrict__ Xfp,
                                             const unsigned char* __restrict__ Wp,
                                             const float* __restrict__ bias,
                                             const int* __restrict__ beam,
                                             const int* __restrict__ blankp,
                                             float* __restrict__ Spart,
                                             float* __restrict__ selL,
                                             int CB) {
  __shared__ unsigned char Ald[32768];   // A tiles; reused as 64x128 f32 P-matrix
  __shared__ int   selv[31];
  __shared__ float selb[31];

  const int tid = threadIdx.x;
  const int tileN = blockIdx.x & 15;
  const int tileM = blockIdx.x >> 4;     // 0..255 (64-row tiles)
  const int row0 = tileM * 64, col0 = tileN * 256;
  const int bb = row0 >> 9;              // batch of this block (64 | 512)
  const int lane = tid & 63, w = tid >> 6;
  const int l31 = lane & 31, hi = lane >> 5;

  if (tid < 31) {
    int v = (tid == 0) ? *blankp : beam[bb * CB + tid - 1];
    selv[tid] = v;
    selb[tid] = bias[v];
  }

  // stage two consecutive 16-KB packed A tiles: 32 x 1KB linear DMA bursts
  const unsigned char* src = Xfp + (size_t)tileM * 32768;
  #pragma unroll
  for (int i = 0; i < 8; ++i) {
    int off = (w * 8 + i) * 1024;
    __builtin_amdgcn_global_load_lds((const GLOBAL_AS void*)(src + off + lane * 16),
                                     (LDS_AS void*)(Ald + off), 16, 0, 0);
  }
  __syncthreads();

  const int colw = col0 + w * 64;
  const int cb = tileN * 4 + w;

  f32x16 acc[2][2];                      // acc[ct][mt]
  #pragma unroll
  for (int ct = 0; ct < 2; ++ct)
    #pragma unroll
    for (int mt = 0; mt < 2; ++mt)
      #pragma unroll
      for (int r = 0; r < 16; ++r) acc[ct][mt][r] = 0.f;

  const unsigned char* wpB = Wp + (size_t)cb * 32768 + lane * 16;
  const unsigned char* aB  = Ald + lane * 16;

  // depth-2 B pipeline: bA = kb (current), bB = kb+1, bC = kb+2 (issuing)
  i32x8 bA[2], bB[2];
  bA[0] = ld2(wpB);        bA[1] = ld2(wpB + 2048);
  bB[0] = ld2(wpB + 4096); bB[1] = ld2(wpB + 4096 + 2048);

  #pragma unroll 1                       // REAL loop: bounds live ranges (anti-spill)
  for (int kb = 0; kb < 8; ++kb) {
    i32x8 bC[2];
    const int kn = (kb < 6) ? kb + 2 : 7;   // depth-2 B prefetch
    bC[0] = ld2(wpB + kn * 4096);
    bC[1] = ld2(wpB + kn * 4096 + 2048);
    {
      i32x8 af0 = ld2(aB + kb * 2048);               // mt = 0 tile
      acc[0][0] = __builtin_amdgcn_mfma_scale_f32_32x32x64_f8f6f4(
          af0, bA[0], acc[0][0], 0, 0, 0, 0x7f7f7f7f, 0, 0x7b7b7b7b);
      acc[1][0] = __builtin_amdgcn_mfma_scale_f32_32x32x64_f8f6f4(
          af0, bA[1], acc[1][0], 0, 0, 0, 0x7f7f7f7f, 0, 0x7b7b7b7b);
    }
    {
      i32x8 af1 = ld2(aB + 16384 + kb * 2048);       // mt = 1 tile
      acc[0][1] = __builtin_amdgcn_mfma_scale_f32_32x32x64_f8f6f4(
          af1, bA[0], acc[0][1], 0, 0, 0, 0x7f7f7f7f, 0, 0x7b7b7b7b);
      acc[1][1] = __builtin_amdgcn_mfma_scale_f32_32x32x64_f8f6f4(
          af1, bA[1], acc[1][1], 0, 0, 0, 0x7f7f7f7f, 0, 0x7b7b7b7b);
    }
    bA[0] = bB[0]; bA[1] = bB[1];
    bB[0] = bC[0]; bB[1] = bC[1];
  }
  // scale_a = 2^0 (e8m0 127), scale_b = 2^-4 (123) undoes W x16 -> true logits

  // epilogue 1 v2: LDS-matrix row-sum.
  // C layout (32x32): col = ct*32 + l31, row = mt*32 + (reg&3)+8*(reg>>2)+4*hi.
  // P[row][f], f = w*32+l31; lane writes 32 partials (one per row it holds),
  // 16-B chunk index swizzled by row&31. Then 64 threads sum their row.
  __syncthreads();                       // all waves done reading Ald
  float* P = (float*)Ald;

  float bvl[2];
  #pragma unroll
  for (int ct = 0; ct < 2; ++ct)
    bvl[ct] = bias[colw + ct * 32 + l31] * L2E;

  {
    const int f = w * 32 + l31;          // 0..127
    const int chunk = f >> 2, elem = f & 3;
    #pragma unroll
    for (int mt = 0; mt < 2; ++mt) {
      #pragma unroll
      for (int reg = 0; reg < 16; ++reg) {
        float s = fexp2(acc[0][mt][reg] * L2E + bvl[0]) +
                  fexp2(acc[1][mt][reg] * L2E + bvl[1]);
        int r31 = (reg & 3) + 8 * (reg >> 2) + 4 * hi;   // row & 31
        int row = mt * 32 + r31;
        P[row * 128 + ((chunk ^ r31) << 2) + elem] = s;
      }
    }
  }
  __syncthreads();
  if (tid < 64) {
    const int r31 = tid & 31;
    f32x4 v = {0.f, 0.f, 0.f, 0.f};
    #pragma unroll
    for (int i = 0; i < 32; ++i)         // read all 32 chunks, XOR order
      v += *(const f32x4*)&P[tid * 128 + ((i ^ r31) << 2)];
    Spart[(size_t)tileN * BT + row0 + tid] = v[0] + v[1] + v[2] + v[3];
  }

  // epilogue 2: beam-column scatter (raw ln-domain logit + bias).
  // selv[s]/colw wave-uniform -> readfirstlane + scalar branch skips ~29/31
  // beams with zero VALU. ct static (no runtime acc indexing).
  const int tbase = row0 & 511;
  #pragma unroll 1
  for (int s = 0; s < 31; ++s) {
    const int vsel = __builtin_amdgcn_readfirstlane(selv[s]);
    const int local = vsel - colw;
    if (local >= 0 && local < 32) {       // scalar branch, ct = 0
      const float bvs = selb[s];
      if (l31 == local) {
        #pragma unroll
        for (int mt = 0; mt < 2; ++mt)
          #pragma unroll
          for (int reg = 0; reg < 16; ++reg) {
            int t = tbase + mt * 32 + (reg & 3) + 8 * (reg >> 2) + 4 * hi;
            selL[((size_t)bb * Tt + t) * 31 + s] = acc[0][mt][reg] + bvs;
          }
      }
    } else if (local >= 32 && local < 64) {  // scalar branch, ct = 1
      const float bvs = selb[s];
      if (l31 == (local & 31)) {
        #pragma unroll
        for (int mt = 0; mt < 2; ++mt)
          #pragma unroll
          for (int reg = 0; reg < 16; ++reg) {
            int t = tbase + mt * 32 + (reg & 3) + 8 * (reg >> 2) + 4 * hi;
            selL[((size_t)bb * Tt + t) * 31 + s] = acc[1][mt][reg] + bvs;
          }
      }
    }
  }
}

// ---- CTC DP + output assembly, log2 domain. grid: B blocks x 256 threads ----
// (R9 rotated-load version — control.) Iteration t's four LDS reads issue at
// t-1 (values carried in registers), final iteration peeled; bit-exact.
__global__ __launch_bounds__(256) void kC(const float* __restrict__ selL,
                                          const float* __restrict__ Spart,
                                          const int* __restrict__ xl,
                                          const int* __restrict__ beam,
                                          const int* __restrict__ blankp,
                                          const int* __restrict__ eosp,
                                          float* __restrict__ out,
                                          int Ly, int CB) {
  __shared__ float sl[Tt * 31];     // raw logits * log2(e)
  __shared__ float lgS[Tt];         // log2(sum_exp)
  __shared__ float lastP1[Tt];      // log2-domain blank cumsum
  __shared__ float blankLp[Tt];     // log2-domain blank logp
  const int b = blockIdx.x, tid = threadIdx.x;

  for (int i = tid; i < Tt * 31; i += 256)
    sl[i] = selL[(size_t)b * Tt * 31 + i] * L2E;
  for (int tt = tid; tt < Tt; tt += 256) {
    float s = 0.f;
    #pragma unroll
    for (int n = 0; n < 16; ++n) s += Spart[(size_t)n * BT + b * Tt + tt];
    lgS[tt] = flog2(s);
  }
  __syncthreads();

  float* orow = out + (size_t)b * Vv;
  for (int i = tid; i < Vv; i += 256) orow[i] = LOGZERO;

  const int xlb = xl[b];
  float curP = LOGZERO;
  if (tid < 64) {
    const int lane = tid;
    float vloc[8];
    float run = 0.f;
    #pragma unroll
    for (int u = 0; u < 8; ++u) {
      int t = lane * 8 + u;
      float bl = sl[t * 31] - lgS[t];
      blankLp[t] = bl;
      run += bl;
      vloc[u] = run;
    }
    float inc = run;
    #pragma unroll
    for (int off = 1; off < 64; off <<= 1) {
      float o = __shfl_up(inc, off, 64);
      if (lane >= off) inc += o;
    }
    float excl = inc - run;
    #pragma unroll
    for (int u = 0; u < 8; ++u) lastP1[lane * 8 + u] = vloc[u] + excl;

    const int kk = (lane < CB) ? lane : (CB - 1);
    const float LOG2ZERO = LOGZERO * L2E;
    float Pn = LOG2ZERO, Pb = LOG2ZERO;
    float mrun = -3.0e38f, srun = 0.0f;
    int start = (Ly < Tt - 1) ? Ly : (Tt - 1);
    if (start == 0) {
      Pn = sl[1 + kk] - lgS[0];
      float vv = (0 < xlb) ? lg2add(Pn, Pb) : LOG2ZERO;
      float nm = fmaxf(mrun, vv);
      srun = srun * fexp2(mrun - nm) + fexp2(vv - nm);
      mrun = nm;
    }
    int t0 = (start > 1) ? start : 1;
    // rotated loads: current iteration's operands live in registers; next
    // iteration's LDS reads issue before the dependent compute.
    float sl_c = sl[t0 * 31 + 1 + kk];
    float lg_c = lgS[t0];
    float xb_c = blankLp[t0];
    float pf_c = lastP1[t0 - 1];      // lastPsum == lastP1 bit-exactly
    #pragma unroll 2
    for (int t = t0; t < Tt - 1; ++t) {
      float sl_n = sl[(t + 1) * 31 + 1 + kk];
      float lg_n = lgS[t + 1];
      float xb_n = blankLp[t + 1];
      float pf_n = lastP1[t];
      float xn = sl_c - lg_c;
      float Pn2 = lg2add(Pn, pf_c) + xn;
      float Pb2 = lg2add(Pn, Pb) + xb_c;
      Pn = Pn2; Pb = Pb2;
      float vv = (t < xlb) ? lg2add(Pn, Pb) : LOG2ZERO;   // off critical path
      float nm = fmaxf(mrun, vv);
      srun = srun * fexp2(mrun - nm) + fexp2(vv - nm);
      mrun = nm;
      sl_c = sl_n; lg_c = lg_n; xb_c = xb_n; pf_c = pf_n;
    }
    {   // peeled final iteration t = Tt-1
      const int t = Tt - 1;
      float xn = sl_c - lg_c;
      float Pn2 = lg2add(Pn, pf_c) + xn;
      float Pb2 = lg2add(Pn, Pb) + xb_c;
      Pn = Pn2; Pb = Pb2;
      float vv = (t < xlb) ? lg2add(Pn, Pb) : LOG2ZERO;
      float nm = fmaxf(mrun, vv);
      srun = srun * fexp2(mrun - nm) + fexp2(vv - nm);
      mrun = nm;
    }
    curP = (mrun + flog2(srun)) * LN2;       // back to ln domain
  }
  __syncthreads();   // LOGZERO fill + lastP1 complete

  if (tid < 64) {
    if (tid < CB) orow[beam[b * CB + tid]] = curP;
  }
  __syncthreads();
  if (tid == 0) {
    float eosv = (xlb >= 1) ? lastP1[xlb - 1] * LN2 : 0.0f;
    orow[*eosp] = eosv;
    orow[*blankp] = LOGZERO;
  }
}

extern "C" void kernel_launch(void* const* d_in, const int* in_sizes, int n_in,
                              void* d_out, int out_size, void* d_ws, size_t ws_size,
                              hipStream_t stream) {
  (void)n_in; (void)out_size; (void)ws_size;
  const float* x    = (const float*)d_in[0];
  const float* W    = (const float*)d_in[1];
  const float* bias = (const float*)d_in[2];
  const int* xl     = (const int*)d_in[3];
  const int* beam   = (const int*)d_in[5];
  const int* blankp = (const int*)d_in[6];
  const int* eosp   = (const int*)d_in[7];
  const int Ly = in_sizes[4] / Bb;
  const int CB = in_sizes[5] / Bb;

  float* Spart = (float*)d_ws;                                            // 1 MB
  float* selL  = (float*)((char*)d_ws + (size_t)0x100000);                // 2.03 MB
  unsigned char* Xfp = (unsigned char*)((char*)d_ws + (size_t)0x400000);  // 8 MB
  unsigned char* Wp  = (unsigned char*)((char*)d_ws + (size_t)0xC00000);  // 2 MB
  float* outf = (float*)d_out;

  kPre<<<640, 256, 0, stream>>>(x, W, Xfp, Wp);
  kA<<<4096, 256, 0, stream>>>(Xfp, Wp, bias, beam, blankp, Spart, selL, CB);
  kC<<<Bb, 256, 0, stream>>>(selL, Spart, xl, beam, blankp, eosp, outf, Ly, CB);
}

// Round 12
// 209.662 us; speedup vs baseline: 1.0246x; 1.0246x over previous
//
#include <hip/hip_runtime.h>
#include <hip/hip_fp8.h>

#define LOGZERO -4290774016.0f   // -(65504^2), exactly representable in fp32
#define L2E 1.4426950408889634f  // log2(e)
#define LN2 0.6931471805599453f

constexpr int Bb = 32, Tt = 512, Dd = 512, Vv = 4096;
constexpr int BT = Bb * Tt;

typedef __attribute__((ext_vector_type(4)))  float f32x4;
typedef __attribute__((ext_vector_type(16))) float f32x16;
typedef __attribute__((ext_vector_type(4)))  int   i32x4;
typedef __attribute__((ext_vector_type(8)))  int   i32x8;

#define GLOBAL_AS __attribute__((address_space(1)))
#define LDS_AS    __attribute__((address_space(3)))

__device__ __forceinline__ float fexp2(float x) { return __builtin_amdgcn_exp2f(x); }  // 2^x
__device__ __forceinline__ float flog2(float x) { return __builtin_amdgcn_logf(x); }   // log2(x)

// pack 4 floats (scaled) -> 4 OCP e4m3 bytes
__device__ __forceinline__ unsigned cvt4_fp8(float4 v, float s) {
#if __has_builtin(__builtin_amdgcn_cvt_pk_fp8_f32)
  int p = __builtin_amdgcn_cvt_pk_fp8_f32(v.x * s, v.y * s, 0, false);
  p = __builtin_amdgcn_cvt_pk_fp8_f32(v.z * s, v.w * s, p, true);
  return (unsigned)p;
#else
  unsigned b0 = __hip_cvt_float_to_fp8(v.x * s, __HIP_SATFINITE, __HIP_E4M3);
  unsigned b1 = __hip_cvt_float_to_fp8(v.y * s, __HIP_SATFINITE, __HIP_E4M3);
  unsigned b2 = __hip_cvt_float_to_fp8(v.z * s, __HIP_SATFINITE, __HIP_E4M3);
  unsigned b3 = __hip_cvt_float_to_fp8(v.w * s, __HIP_SATFINITE, __HIP_E4M3);
  return b0 | (b1 << 8) | (b2 << 16) | (b3 << 24);
#endif
}

// logaddexp in the log2 domain
__device__ __forceinline__ float lg2add(float a, float b) {
  float mx = fmaxf(a, b);
  float d  = fabsf(a - b);
  return mx + flog2(1.0f + fexp2(-d));
}

// load two b128 slots 1 KB apart and concat into an i32x8 MFMA operand
__device__ __forceinline__ i32x8 ld2(const unsigned char* p) {
  i32x4 lo = *(const i32x4*)p;
  i32x4 hx = *(const i32x4*)(p + 1024);
  return __builtin_shufflevector(lo, hx, 0, 1, 2, 3, 4, 5, 6, 7);
}

// ---- kPre v2: LDS-transposed coalesced pack into fp8 fragment layouts ----
// (unchanged — control). One block per 32-row output tile. Phase 1 reads
// contiguous 1-KB bursts/wave, converts, XOR-swizzled LDS store; phase 2
// gathers b128 fragment slots + 1-KB coalesced global stores.
// Xfp tile tM (16 KB): slot16 = (kb*2+h)*64 + khalf*32 + r
//   = fp8( x[tM*32+r][kb*64 + khalf*32 + h*16 + j] ), j=0..15
// Wp tile cb (32 KB): slot16 = (kb*4+ct*2+h)*64 + khalf*32 + r
//   = fp8( 16 * W[cb*64+ct*32+r][kb*64 + khalf*32 + h*16 + j] )
__global__ __launch_bounds__(256) void kPre(const float* __restrict__ x,
                                            const float* __restrict__ W,
                                            unsigned char* __restrict__ Xfp,
                                            unsigned char* __restrict__ Wp) {
  __shared__ unsigned char T[16384];
  const int tid = threadIdx.x, bid = blockIdx.x;
  const bool isX = bid < 512;
  const float* srcF;
  float scale;
  int cb = 0, half = 0;
  if (isX) {
    srcF = x + (size_t)bid * 32 * Dd;            // 32 contiguous rows
    scale = 1.0f;
  } else {
    int idx = bid - 512;                          // 0..127
    cb = idx >> 1; half = idx & 1;
    srcF = W + ((size_t)cb * 64 + half * 32) * Dd;
    scale = 16.0f;                                // x16 prescale (undone by MX scale_b)
  }

  // phase 1: fully-coalesced loads -> fp8 -> swizzled LDS
  #pragma unroll
  for (int p = 0; p < 16; ++p) {
    int f = p * 256 + tid;                        // float4 index 0..4095
    int r = f >> 7;                               // row 0..31
    int cf = f & 127;
    int c = cf >> 2, m = cf & 3;                  // 16-float chunk, float4 within
    float4 v = *(const float4*)(srcF + (size_t)f * 4);
    unsigned o = cvt4_fp8(v, scale);
    *(unsigned*)(T + ((r * 32 + (c ^ r)) * 16 + m * 4)) = o;
  }
  __syncthreads();

  // phase 2: gather fragment slots, 1-KB coalesced stores
  if (isX) {
    unsigned char* dst = Xfp + (size_t)bid * 16384;
    #pragma unroll
    for (int u = 0; u < 4; ++u) {
      int s = u * 256 + tid;                      // slot 0..1023
      int r = s & 31, khalf = (s >> 5) & 1, h = (s >> 6) & 1, kb = s >> 7;
      int c = kb * 4 + khalf * 2 + h;
      uint4 o = *(const uint4*)(T + (r * 32 + (c ^ r)) * 16);
      *(uint4*)(dst + (size_t)s * 16) = o;
    }
  } else {
    unsigned char* dst = Wp + (size_t)cb * 32768;
    #pragma unroll
    for (int u = 0; u < 4; ++u) {
      int lsl = u * 256 + tid;                    // local slot 0..1023 (ct=half)
      int r = lsl & 31, khalf = (lsl >> 5) & 1, h = (lsl >> 6) & 1, kb = lsl >> 7;
      int c = kb * 4 + khalf * 2 + h;
      int s = kb * 256 + half * 128 + h * 64 + khalf * 32 + r;
      uint4 o = *(const uint4*)(T + (r * 32 + (c ^ r)) * 16);
      *(uint4*)(dst + (size_t)s * 16) = o;
    }
  }
}

// ---- fully barrier-free MX-fp8 GEMM + exp-sum partials + beam scatter ----
// grid 4096, 256 threads (4 waves). Block = 64 rows x 256 cols, full K=512.
// R12 change: NO LDS A-STAGING. R11 post-mortem: every K-loop/occupancy/
// prefetch variant lands 71-93 us vs a ~35-us composed floor; the one
// never-probed structure is the block-prologue global_load_lds + full
// __syncthreads barrier-drain, paid at every one of 16 block generations
// per CU. The LDS A-tile's only value was sharing the A fetch across 4
// waves (saves 384 MB of L2 read -- trivial vs the 34.5 TB/s ceiling).
// Now: A fragments read straight from Xfp (L2-resident) into registers,
// depth-1 rotated exactly like B. K-loop = pure global->reg->MFMA, ZERO
// barriers, ZERO DS traffic. L2 total ~1 GB (~30 us, overlappable).
// Registers: 64 AGPR acc + aA/aN 32 + bA/bN 32 + ~25 temps ~ 153 ->
// (256,3) cap 170. SPILL GUARD: WRITE_SIZE must stay ~11 MB.
// LDS (32 KB) retained ONLY for the epilogue P-matrix; selv/selb ordering
// is covered by the epilogue's post-write __syncthreads.
__global__ __launch_bounds__(256, 3) void kA(const unsigned char* __restrict__ Xfp,
                                             const unsigned char* __restrict__ Wp,
                                             const float* __restrict__ bias,
                                             const int* __restrict__ beam,
                                             const int* __restrict__ blankp,
                                             float* __restrict__ Spart,
                                             float* __restrict__ selL,
                                             int CB) {
  __shared__ unsigned char Ald[32768];   // epilogue 64x128 f32 P-matrix only
  __shared__ int   selv[31];
  __shared__ float selb[31];

  const int tid = threadIdx.x;
  const int tileN = blockIdx.x & 15;
  const int tileM = blockIdx.x >> 4;     // 0..255 (64-row tiles)
  const int row0 = tileM * 64, col0 = tileN * 256;
  const int bb = row0 >> 9;              // batch of this block (64 | 512)
  const int lane = tid & 63, w = tid >> 6;
  const int l31 = lane & 31, hi = lane >> 5;

  if (tid < 31) {
    int v = (tid == 0) ? *blankp : beam[bb * CB + tid - 1];
    selv[tid] = v;
    selb[tid] = bias[v];
  }

  const int colw = col0 + w * 64;
  const int cb = tileN * 4 + w;

  f32x16 acc[2][2];                      // acc[ct][mt]
  #pragma unroll
  for (int ct = 0; ct < 2; ++ct)
    #pragma unroll
    for (int mt = 0; mt < 2; ++mt)
      #pragma unroll
      for (int r = 0; r < 16; ++r) acc[ct][mt][r] = 0.f;

  const unsigned char* wpB = Wp + (size_t)cb * 32768 + lane * 16;
  const unsigned char* aG  = Xfp + (size_t)tileM * 32768 + lane * 16;

  // depth-1 rotation for BOTH operands (current regs + issuing next)
  i32x8 bA[2], aA[2];
  bA[0] = ld2(wpB);       bA[1] = ld2(wpB + 2048);
  aA[0] = ld2(aG);        aA[1] = ld2(aG + 16384);

  #pragma unroll 1                       // REAL loop: bounds live ranges (anti-spill)
  for (int kb = 0; kb < 8; ++kb) {
    const int kn = (kb < 7) ? kb + 1 : 7;
    i32x8 bN[2], aN[2];
    bN[0] = ld2(wpB + kn * 4096);
    bN[1] = ld2(wpB + kn * 4096 + 2048);
    aN[0] = ld2(aG + kn * 2048);             // mt = 0 tile
    aN[1] = ld2(aG + 16384 + kn * 2048);     // mt = 1 tile
    #pragma unroll
    for (int mt = 0; mt < 2; ++mt) {
      acc[0][mt] = __builtin_amdgcn_mfma_scale_f32_32x32x64_f8f6f4(
          aA[mt], bA[0], acc[0][mt], 0, 0, 0, 0x7f7f7f7f, 0, 0x7b7b7b7b);
      acc[1][mt] = __builtin_amdgcn_mfma_scale_f32_32x32x64_f8f6f4(
          aA[mt], bA[1], acc[1][mt], 0, 0, 0, 0x7f7f7f7f, 0, 0x7b7b7b7b);
    }
    bA[0] = bN[0]; bA[1] = bN[1];
    aA[0] = aN[0]; aA[1] = aN[1];
  }
  // scale_a = 2^0 (e8m0 127), scale_b = 2^-4 (123) undoes W x16 -> true logits

  // epilogue 1: LDS-matrix row-sum (R8's winner).
  // C layout (32x32): col = ct*32 + l31, row = mt*32 + (reg&3)+8*(reg>>2)+4*hi.
  // P[row][f], f = w*32+l31; lane writes 32 partials (one per row it holds),
  // 16-B chunk index swizzled by row&31. Then 64 threads sum their row.
  float* P = (float*)Ald;

  float bvl[2];
  #pragma unroll
  for (int ct = 0; ct < 2; ++ct)
    bvl[ct] = bias[colw + ct * 32 + l31] * L2E;

  {
    const int f = w * 32 + l31;          // 0..127
    const int chunk = f >> 2, elem = f & 3;
    #pragma unroll
    for (int mt = 0; mt < 2; ++mt) {
      #pragma unroll
      for (int reg = 0; reg < 16; ++reg) {
        float s = fexp2(acc[0][mt][reg] * L2E + bvl[0]) +
                  fexp2(acc[1][mt][reg] * L2E + bvl[1]);
        int r31 = (reg & 3) + 8 * (reg >> 2) + 4 * hi;   // row & 31
        int row = mt * 32 + r31;
        P[row * 128 + ((chunk ^ r31) << 2) + elem] = s;
      }
    }
  }
  __syncthreads();                       // P complete; also orders selv/selb
  if (tid < 64) {
    const int r31 = tid & 31;
    f32x4 v = {0.f, 0.f, 0.f, 0.f};
    #pragma unroll
    for (int i = 0; i < 32; ++i)         // read all 32 chunks, XOR order
      v += *(const f32x4*)&P[tid * 128 + ((i ^ r31) << 2)];
    Spart[(size_t)tileN * BT + row0 + tid] = v[0] + v[1] + v[2] + v[3];
  }

  // epilogue 2: beam-column scatter (raw ln-domain logit + bias).
  // selv[s]/colw wave-uniform -> readfirstlane + scalar branch skips ~29/31
  // beams with zero VALU. ct static (no runtime acc indexing).
  const int tbase = row0 & 511;
  #pragma unroll 1
  for (int s = 0; s < 31; ++s) {
    const int vsel = __builtin_amdgcn_readfirstlane(selv[s]);
    const int local = vsel - colw;
    if (local >= 0 && local < 32) {       // scalar branch, ct = 0
      const float bvs = selb[s];
      if (l31 == local) {
        #pragma unroll
        for (int mt = 0; mt < 2; ++mt)
          #pragma unroll
          for (int reg = 0; reg < 16; ++reg) {
            int t = tbase + mt * 32 + (reg & 3) + 8 * (reg >> 2) + 4 * hi;
            selL[((size_t)bb * Tt + t) * 31 + s] = acc[0][mt][reg] + bvs;
          }
      }
    } else if (local >= 32 && local < 64) {  // scalar branch, ct = 1
      const float bvs = selb[s];
      if (l31 == (local & 31)) {
        #pragma unroll
        for (int mt = 0; mt < 2; ++mt)
          #pragma unroll
          for (int reg = 0; reg < 16; ++reg) {
            int t = tbase + mt * 32 + (reg & 3) + 8 * (reg >> 2) + 4 * hi;
            selL[((size_t)bb * Tt + t) * 31 + s] = acc[1][mt][reg] + bvs;
          }
      }
    }
  }
}

// ---- CTC DP + output assembly, log2 domain. grid: B blocks x 256 threads ----
// (R9 rotated-load version — control.) Iteration t's four LDS reads issue at
// t-1 (values carried in registers), final iteration peeled; bit-exact.
__global__ __launch_bounds__(256) void kC(const float* __restrict__ selL,
                                          const float* __restrict__ Spart,
                                          const int* __restrict__ xl,
                                          const int* __restrict__ beam,
                                          const int* __restrict__ blankp,
                                          const int* __restrict__ eosp,
                                          float* __restrict__ out,
                                          int Ly, int CB) {
  __shared__ float sl[Tt * 31];     // raw logits * log2(e)
  __shared__ float lgS[Tt];         // log2(sum_exp)
  __shared__ float lastP1[Tt];      // log2-domain blank cumsum
  __shared__ float blankLp[Tt];     // log2-domain blank logp
  const int b = blockIdx.x, tid = threadIdx.x;

  for (int i = tid; i < Tt * 31; i += 256)
    sl[i] = selL[(size_t)b * Tt * 31 + i] * L2E;
  for (int tt = tid; tt < Tt; tt += 256) {
    float s = 0.f;
    #pragma unroll
    for (int n = 0; n < 16; ++n) s += Spart[(size_t)n * BT + b * Tt + tt];
    lgS[tt] = flog2(s);
  }
  __syncthreads();

  float* orow = out + (size_t)b * Vv;
  for (int i = tid; i < Vv; i += 256) orow[i] = LOGZERO;

  const int xlb = xl[b];
  float curP = LOGZERO;
  if (tid < 64) {
    const int lane = tid;
    float vloc[8];
    float run = 0.f;
    #pragma unroll
    for (int u = 0; u < 8; ++u) {
      int t = lane * 8 + u;
      float bl = sl[t * 31] - lgS[t];
      blankLp[t] = bl;
      run += bl;
      vloc[u] = run;
    }
    float inc = run;
    #pragma unroll
    for (int off = 1; off < 64; off <<= 1) {
      float o = __shfl_up(inc, off, 64);
      if (lane >= off) inc += o;
    }
    float excl = inc - run;
    #pragma unroll
    for (int u = 0; u < 8; ++u) lastP1[lane * 8 + u] = vloc[u] + excl;

    const int kk = (lane < CB) ? lane : (CB - 1);
    const float LOG2ZERO = LOGZERO * L2E;
    float Pn = LOG2ZERO, Pb = LOG2ZERO;
    float mrun = -3.0e38f, srun = 0.0f;
    int start = (Ly < Tt - 1) ? Ly : (Tt - 1);
    if (start == 0) {
      Pn = sl[1 + kk] - lgS[0];
      float vv = (0 < xlb) ? lg2add(Pn, Pb) : LOG2ZERO;
      float nm = fmaxf(mrun, vv);
      srun = srun * fexp2(mrun - nm) + fexp2(vv - nm);
      mrun = nm;
    }
    int t0 = (start > 1) ? start : 1;
    // rotated loads: current iteration's operands live in registers; next
    // iteration's LDS reads issue before the dependent compute.
    float sl_c = sl[t0 * 31 + 1 + kk];
    float lg_c = lgS[t0];
    float xb_c = blankLp[t0];
    float pf_c = lastP1[t0 - 1];      // lastPsum == lastP1 bit-exactly
    #pragma unroll 2
    for (int t = t0; t < Tt - 1; ++t) {
      float sl_n = sl[(t + 1) * 31 + 1 + kk];
      float lg_n = lgS[t + 1];
      float xb_n = blankLp[t + 1];
      float pf_n = lastP1[t];
      float xn = sl_c - lg_c;
      float Pn2 = lg2add(Pn, pf_c) + xn;
      float Pb2 = lg2add(Pn, Pb) + xb_c;
      Pn = Pn2; Pb = Pb2;
      float vv = (t < xlb) ? lg2add(Pn, Pb) : LOG2ZERO;   // off critical path
      float nm = fmaxf(mrun, vv);
      srun = srun * fexp2(mrun - nm) + fexp2(vv - nm);
      mrun = nm;
      sl_c = sl_n; lg_c = lg_n; xb_c = xb_n; pf_c = pf_n;
    }
    {   // peeled final iteration t = Tt-1
      const int t = Tt - 1;
      float xn = sl_c - lg_c;
      float Pn2 = lg2add(Pn, pf_c) + xn;
      float Pb2 = lg2add(Pn, Pb) + xb_c;
      Pn = Pn2; Pb = Pb2;
      float vv = (t < xlb) ? lg2add(Pn, Pb) : LOG2ZERO;
      float nm = fmaxf(mrun, vv);
      srun = srun * fexp2(mrun - nm) + fexp2(vv - nm);
      mrun = nm;
    }
    curP = (mrun + flog2(srun)) * LN2;       // back to ln domain
  }
  __syncthreads();   // LOGZERO fill + lastP1 complete

  if (tid < 64) {
    if (tid < CB) orow[beam[b * CB + tid]] = curP;
  }
  __syncthreads();
  if (tid == 0) {
    float eosv = (xlb >= 1) ? lastP1[xlb - 1] * LN2 : 0.0f;
    orow[*eosp] = eosv;
    orow[*blankp] = LOGZERO;
  }
}

extern "C" void kernel_launch(void* const* d_in, const int* in_sizes, int n_in,
                              void* d_out, int out_size, void* d_ws, size_t ws_size,
                              hipStream_t stream) {
  (void)n_in; (void)out_size; (void)ws_size;
  const float* x    = (const float*)d_in[0];
  const float* W    = (const float*)d_in[1];
  const float* bias = (const float*)d_in[2];
  const int* xl     = (const int*)d_in[3];
  const int* beam   = (const int*)d_in[5];
  const int* blankp = (const int*)d_in[6];
  const int* eosp   = (const int*)d_in[7];
  const int Ly = in_sizes[4] / Bb;
  const int CB = in_sizes[5] / Bb;

  float* Spart = (float*)d_ws;                                            // 1 MB
  float* selL  = (float*)((char*)d_ws + (size_t)0x100000);                // 2.03 MB
  unsigned char* Xfp = (unsigned char*)((char*)d_ws + (size_t)0x400000);  // 8 MB
  unsigned char* Wp  = (unsigned char*)((char*)d_ws + (size_t)0xC00000);  // 2 MB
  float* outf = (float*)d_out;

  kPre<<<640, 256, 0, stream>>>(x, W, Xfp, Wp);
  kA<<<4096, 256, 0, stream>>>(Xfp, Wp, bias, beam, blankp, Spart, selL, CB);
  kC<<<Bb, 256, 0, stream>>>(selL, Spart, xl, beam, blankp, eosp, outf, Ly, CB);
}

// Round 14
// 206.105 us; speedup vs baseline: 1.0423x; 1.0173x over previous
//
#include <hip/hip_runtime.h>
#include <hip/hip_fp8.h>

#define LOGZERO -4290774016.0f   // -(65504^2), exactly representable in fp32
#define L2E 1.4426950408889634f  // log2(e)
#define LN2 0.6931471805599453f

constexpr int Bb = 32, Tt = 512, Dd = 512, Vv = 4096;
constexpr int BT = Bb * Tt;

typedef __attribute__((ext_vector_type(4)))  float f32x4;
typedef __attribute__((ext_vector_type(16))) float f32x16;
typedef __attribute__((ext_vector_type(4)))  int   i32x4;
typedef __attribute__((ext_vector_type(8)))  int   i32x8;

#define GLOBAL_AS __attribute__((address_space(1)))
#define LDS_AS    __attribute__((address_space(3)))

__device__ __forceinline__ float fexp2(float x) { return __builtin_amdgcn_exp2f(x); }  // 2^x
__device__ __forceinline__ float flog2(float x) { return __builtin_amdgcn_logf(x); }   // log2(x)

// pack 4 floats (scaled) -> 4 OCP e4m3 bytes
__device__ __forceinline__ unsigned cvt4_fp8(float4 v, float s) {
#if __has_builtin(__builtin_amdgcn_cvt_pk_fp8_f32)
  int p = __builtin_amdgcn_cvt_pk_fp8_f32(v.x * s, v.y * s, 0, false);
  p = __builtin_amdgcn_cvt_pk_fp8_f32(v.z * s, v.w * s, p, true);
  return (unsigned)p;
#else
  unsigned b0 = __hip_cvt_float_to_fp8(v.x * s, __HIP_SATFINITE, __HIP_E4M3);
  unsigned b1 = __hip_cvt_float_to_fp8(v.y * s, __HIP_SATFINITE, __HIP_E4M3);
  unsigned b2 = __hip_cvt_float_to_fp8(v.z * s, __HIP_SATFINITE, __HIP_E4M3);
  unsigned b3 = __hip_cvt_float_to_fp8(v.w * s, __HIP_SATFINITE, __HIP_E4M3);
  return b0 | (b1 << 8) | (b2 << 16) | (b3 << 24);
#endif
}

// logaddexp in the log2 domain
__device__ __forceinline__ float lg2add(float a, float b) {
  float mx = fmaxf(a, b);
  float d  = fabsf(a - b);
  return mx + flog2(1.0f + fexp2(-d));
}

// load two b128 slots 1 KB apart and concat into an i32x8 MFMA operand
__device__ __forceinline__ i32x8 ld2(const unsigned char* p) {
  i32x4 lo = *(const i32x4*)p;
  i32x4 hx = *(const i32x4*)(p + 1024);
  return __builtin_shufflevector(lo, hx, 0, 1, 2, 3, 4, 5, 6, 7);
}

// ---- kPre v2: LDS-transposed coalesced pack into fp8 fragment layouts ----
// (unchanged — control). One block per 32-row output tile. Phase 1 reads
// contiguous 1-KB bursts/wave, converts, XOR-swizzled LDS store; phase 2
// gathers b128 fragment slots + 1-KB coalesced global stores.
// Xfp tile tM (16 KB): slot16 = (kb*2+h)*64 + khalf*32 + r
//   = fp8( x[tM*32+r][kb*64 + khalf*32 + h*16 + j] ), j=0..15
// Wp tile cb (32 KB): slot16 = (kb*4+ct*2+h)*64 + khalf*32 + r
//   = fp8( 16 * W[cb*64+ct*32+r][kb*64 + khalf*32 + h*16 + j] )
__global__ __launch_bounds__(256) void kPre(const float* __restrict__ x,
                                            const float* __restrict__ W,
                                            unsigned char* __restrict__ Xfp,
                                            unsigned char* __restrict__ Wp) {
  __shared__ unsigned char T[16384];
  const int tid = threadIdx.x, bid = blockIdx.x;
  const bool isX = bid < 512;
  const float* srcF;
  float scale;
  int cb = 0, half = 0;
  if (isX) {
    srcF = x + (size_t)bid * 32 * Dd;            // 32 contiguous rows
    scale = 1.0f;
  } else {
    int idx = bid - 512;                          // 0..127
    cb = idx >> 1; half = idx & 1;
    srcF = W + ((size_t)cb * 64 + half * 32) * Dd;
    scale = 16.0f;                                // x16 prescale (undone by MX scale_b)
  }

  // phase 1: fully-coalesced loads -> fp8 -> swizzled LDS
  #pragma unroll
  for (int p = 0; p < 16; ++p) {
    int f = p * 256 + tid;                        // float4 index 0..4095
    int r = f >> 7;                               // row 0..31
    int cf = f & 127;
    int c = cf >> 2, m = cf & 3;                  // 16-float chunk, float4 within
    float4 v = *(const float4*)(srcF + (size_t)f * 4);
    unsigned o = cvt4_fp8(v, scale);
    *(unsigned*)(T + ((r * 32 + (c ^ r)) * 16 + m * 4)) = o;
  }
  __syncthreads();

  // phase 2: gather fragment slots, 1-KB coalesced stores
  if (isX) {
    unsigned char* dst = Xfp + (size_t)bid * 16384;
    #pragma unroll
    for (int u = 0; u < 4; ++u) {
      int s = u * 256 + tid;                      // slot 0..1023
      int r = s & 31, khalf = (s >> 5) & 1, h = (s >> 6) & 1, kb = s >> 7;
      int c = kb * 4 + khalf * 2 + h;
      uint4 o = *(const uint4*)(T + (r * 32 + (c ^ r)) * 16);
      *(uint4*)(dst + (size_t)s * 16) = o;
    }
  } else {
    unsigned char* dst = Wp + (size_t)cb * 32768;
    #pragma unroll
    for (int u = 0; u < 4; ++u) {
      int lsl = u * 256 + tid;                    // local slot 0..1023 (ct=half)
      int r = lsl & 31, khalf = (lsl >> 5) & 1, h = (lsl >> 6) & 1, kb = lsl >> 7;
      int c = kb * 4 + khalf * 2 + h;
      int s = kb * 256 + half * 128 + h * 64 + khalf * 32 + r;
      uint4 o = *(const uint4*)(T + (r * 32 + (c ^ r)) * 16);
      *(uint4*)(dst + (size_t)s * 16) = o;
    }
  }
}

// ---- barrier-free MX-fp8 GEMM + exp-sum partials + beam scatter ----
// grid 4096, 256 threads (4 waves). Block = 64 rows x 256 cols, full K=512.
// R13 analysis: VALUBusy 72% ~ 51 of kA's 71 us — the unexplained saturated
// counter. Culprit in source: the K-loop's REGISTER ROTATION (bA[..]=bN[..];
// aA[..]=aN[..]) = 32 v_mov/iter + ld2 marshalling movs under unroll-1's
// single-name allocation — ~300-500 mov-class VALU ops/thread/tile, present
// in every 71-75 us variant.
// R14 change: PING-PONG UNROLL-2 — two named register sets; even sub-step
// computes set0 while loading set1, odd vice versa. Zero copies; same loads,
// same MFMA order, bit-identical accumulation. Direct-global A (R12), zero
// K-loop barriers. Regs: 64 AGPR acc + 64 operand + ~25 temps ~ 153 < 170
// cap of (256,3). SPILL GUARD: WRITE_SIZE must stay ~11 MB.
// LDS (32 KB) retained ONLY for the epilogue P-matrix.
__global__ __launch_bounds__(256, 3) void kA(const unsigned char* __restrict__ Xfp,
                                             const unsigned char* __restrict__ Wp,
                                             const float* __restrict__ bias,
                                             const int* __restrict__ beam,
                                             const int* __restrict__ blankp,
                                             float* __restrict__ Spart,
                                             float* __restrict__ selL,
                                             int CB) {
  __shared__ unsigned char Ald[32768];   // epilogue 64x128 f32 P-matrix only
  __shared__ int   selv[31];
  __shared__ float selb[31];

  const int tid = threadIdx.x;
  const int tileN = blockIdx.x & 15;
  const int tileM = blockIdx.x >> 4;     // 0..255 (64-row tiles)
  const int row0 = tileM * 64, col0 = tileN * 256;
  const int bb = row0 >> 9;              // batch of this block (64 | 512)
  const int lane = tid & 63, w = tid >> 6;
  const int l31 = lane & 31, hi = lane >> 5;

  if (tid < 31) {
    int v = (tid == 0) ? *blankp : beam[bb * CB + tid - 1];
    selv[tid] = v;
    selb[tid] = bias[v];
  }

  const int colw = col0 + w * 64;
  const int cb = tileN * 4 + w;

  f32x16 acc[2][2];                      // acc[ct][mt]
  #pragma unroll
  for (int ct = 0; ct < 2; ++ct)
    #pragma unroll
    for (int mt = 0; mt < 2; ++mt)
      #pragma unroll
      for (int r = 0; r < 16; ++r) acc[ct][mt][r] = 0.f;

  const unsigned char* wpB = Wp + (size_t)cb * 32768 + lane * 16;
  const unsigned char* aG  = Xfp + (size_t)tileM * 32768 + lane * 16;

  // ping-pong operand sets: set0 = even kb, set1 = odd kb. No rotation movs.
  i32x8 a0[2], b0[2], a1[2], b1[2];
  b0[0] = ld2(wpB);        b0[1] = ld2(wpB + 2048);
  a0[0] = ld2(aG);         a0[1] = ld2(aG + 16384);

  #pragma unroll 1                       // REAL loop: bounds live ranges
  for (int kb = 0; kb < 8; kb += 2) {
    // issue kb+1 loads into set1 (kb+1 <= 7 always)
    b1[0] = ld2(wpB + (kb + 1) * 4096);
    b1[1] = ld2(wpB + (kb + 1) * 4096 + 2048);
    a1[0] = ld2(aG + (kb + 1) * 2048);
    a1[1] = ld2(aG + 16384 + (kb + 1) * 2048);
    // MFMA on set0 (kb)
    #pragma unroll
    for (int mt = 0; mt < 2; ++mt) {
      acc[0][mt] = __builtin_amdgcn_mfma_scale_f32_32x32x64_f8f6f4(
          a0[mt], b0[0], acc[0][mt], 0, 0, 0, 0x7f7f7f7f, 0, 0x7b7b7b7b);
      acc[1][mt] = __builtin_amdgcn_mfma_scale_f32_32x32x64_f8f6f4(
          a0[mt], b0[1], acc[1][mt], 0, 0, 0, 0x7f7f7f7f, 0, 0x7b7b7b7b);
    }
    // issue kb+2 loads into set0 (clamped; final trip's loads are dead)
    const int kn = (kb < 6) ? kb + 2 : 7;
    b0[0] = ld2(wpB + kn * 4096);
    b0[1] = ld2(wpB + kn * 4096 + 2048);
    a0[0] = ld2(aG + kn * 2048);
    a0[1] = ld2(aG + 16384 + kn * 2048);
    // MFMA on set1 (kb+1)
    #pragma unroll
    for (int mt = 0; mt < 2; ++mt) {
      acc[0][mt] = __builtin_amdgcn_mfma_scale_f32_32x32x64_f8f6f4(
          a1[mt], b1[0], acc[0][mt], 0, 0, 0, 0x7f7f7f7f, 0, 0x7b7b7b7b);
      acc[1][mt] = __builtin_amdgcn_mfma_scale_f32_32x32x64_f8f6f4(
          a1[mt], b1[1], acc[1][mt], 0, 0, 0, 0x7f7f7f7f, 0, 0x7b7b7b7b);
    }
  }
  // scale_a = 2^0 (e8m0 127), scale_b = 2^-4 (123) undoes W x16 -> true logits

  // epilogue 1: LDS-matrix row-sum (R8's winner).
  // C layout (32x32): col = ct*32 + l31, row = mt*32 + (reg&3)+8*(reg>>2)+4*hi.
  // P[row][f], f = w*32+l31; lane writes 32 partials (one per row it holds),
  // 16-B chunk index swizzled by row&31. Then 64 threads sum their row.
  float* P = (float*)Ald;

  float bvl[2];
  #pragma unroll
  for (int ct = 0; ct < 2; ++ct)
    bvl[ct] = bias[colw + ct * 32 + l31] * L2E;

  {
    const int f = w * 32 + l31;          // 0..127
    const int chunk = f >> 2, elem = f & 3;
    #pragma unroll
    for (int mt = 0; mt < 2; ++mt) {
      #pragma unroll
      for (int reg = 0; reg < 16; ++reg) {
        float s = fexp2(acc[0][mt][reg] * L2E + bvl[0]) +
                  fexp2(acc[1][mt][reg] * L2E + bvl[1]);
        int r31 = (reg & 3) + 8 * (reg >> 2) + 4 * hi;   // row & 31
        int row = mt * 32 + r31;
        P[row * 128 + ((chunk ^ r31) << 2) + elem] = s;
      }
    }
  }
  __syncthreads();                       // P complete; also orders selv/selb
  if (tid < 64) {
    const int r31 = tid & 31;
    f32x4 v = {0.f, 0.f, 0.f, 0.f};
    #pragma unroll
    for (int i = 0; i < 32; ++i)         // read all 32 chunks, XOR order
      v += *(const f32x4*)&P[tid * 128 + ((i ^ r31) << 2)];
    Spart[(size_t)tileN * BT + row0 + tid] = v[0] + v[1] + v[2] + v[3];
  }

  // epilogue 2: beam-column scatter (raw ln-domain logit + bias).
  // selv[s]/colw wave-uniform -> readfirstlane + scalar branch skips ~29/31
  // beams with zero VALU. ct static (no runtime acc indexing).
  const int tbase = row0 & 511;
  #pragma unroll 1
  for (int s = 0; s < 31; ++s) {
    const int vsel = __builtin_amdgcn_readfirstlane(selv[s]);
    const int local = vsel - colw;
    if (local >= 0 && local < 32) {       // scalar branch, ct = 0
      const float bvs = selb[s];
      if (l31 == local) {
        #pragma unroll
        for (int mt = 0; mt < 2; ++mt)
          #pragma unroll
          for (int reg = 0; reg < 16; ++reg) {
            int t = tbase + mt * 32 + (reg & 3) + 8 * (reg >> 2) + 4 * hi;
            selL[((size_t)bb * Tt + t) * 31 + s] = acc[0][mt][reg] + bvs;
          }
      }
    } else if (local >= 32 && local < 64) {  // scalar branch, ct = 1
      const float bvs = selb[s];
      if (l31 == (local & 31)) {
        #pragma unroll
        for (int mt = 0; mt < 2; ++mt)
          #pragma unroll
          for (int reg = 0; reg < 16; ++reg) {
            int t = tbase + mt * 32 + (reg & 3) + 8 * (reg >> 2) + 4 * hi;
            selL[((size_t)bb * Tt + t) * 31 + s] = acc[1][mt][reg] + bvs;
          }
      }
    }
  }
}

// ---- CTC DP + output assembly, log2 domain. grid: B blocks x 256 threads ----
// (R9 rotated-load version — control.) Iteration t's four LDS reads issue at
// t-1 (values carried in registers), final iteration peeled; bit-exact.
__global__ __launch_bounds__(256) void kC(const float* __restrict__ selL,
                                          const float* __restrict__ Spart,
                                          const int* __restrict__ xl,
                                          const int* __restrict__ beam,
                                          const int* __restrict__ blankp,
                                          const int* __restrict__ eosp,
                                          float* __restrict__ out,
                                          int Ly, int CB) {
  __shared__ float sl[Tt * 31];     // raw logits * log2(e)
  __shared__ float lgS[Tt];         // log2(sum_exp)
  __shared__ float lastP1[Tt];      // log2-domain blank cumsum
  __shared__ float blankLp[Tt];     // log2-domain blank logp
  const int b = blockIdx.x, tid = threadIdx.x;

  for (int i = tid; i < Tt * 31; i += 256)
    sl[i] = selL[(size_t)b * Tt * 31 + i] * L2E;
  for (int tt = tid; tt < Tt; tt += 256) {
    float s = 0.f;
    #pragma unroll
    for (int n = 0; n < 16; ++n) s += Spart[(size_t)n * BT + b * Tt + tt];
    lgS[tt] = flog2(s);
  }
  __syncthreads();

  float* orow = out + (size_t)b * Vv;
  for (int i = tid; i < Vv; i += 256) orow[i] = LOGZERO;

  const int xlb = xl[b];
  float curP = LOGZERO;
  if (tid < 64) {
    const int lane = tid;
    float vloc[8];
    float run = 0.f;
    #pragma unroll
    for (int u = 0; u < 8; ++u) {
      int t = lane * 8 + u;
      float bl = sl[t * 31] - lgS[t];
      blankLp[t] = bl;
      run += bl;
      vloc[u] = run;
    }
    float inc = run;
    #pragma unroll
    for (int off = 1; off < 64; off <<= 1) {
      float o = __shfl_up(inc, off, 64);
      if (lane >= off) inc += o;
    }
    float excl = inc - run;
    #pragma unroll
    for (int u = 0; u < 8; ++u) lastP1[lane * 8 + u] = vloc[u] + excl;

    const int kk = (lane < CB) ? lane : (CB - 1);
    const float LOG2ZERO = LOGZERO * L2E;
    float Pn = LOG2ZERO, Pb = LOG2ZERO;
    float mrun = -3.0e38f, srun = 0.0f;
    int start = (Ly < Tt - 1) ? Ly : (Tt - 1);
    if (start == 0) {
      Pn = sl[1 + kk] - lgS[0];
      float vv = (0 < xlb) ? lg2add(Pn, Pb) : LOG2ZERO;
      float nm = fmaxf(mrun, vv);
      srun = srun * fexp2(mrun - nm) + fexp2(vv - nm);
      mrun = nm;
    }
    int t0 = (start > 1) ? start : 1;
    // rotated loads: current iteration's operands live in registers; next
    // iteration's LDS reads issue before the dependent compute.
    float sl_c = sl[t0 * 31 + 1 + kk];
    float lg_c = lgS[t0];
    float xb_c = blankLp[t0];
    float pf_c = lastP1[t0 - 1];      // lastPsum == lastP1 bit-exactly
    #pragma unroll 2
    for (int t = t0; t < Tt - 1; ++t) {
      float sl_n = sl[(t + 1) * 31 + 1 + kk];
      float lg_n = lgS[t + 1];
      float xb_n = blankLp[t + 1];
      float pf_n = lastP1[t];
      float xn = sl_c - lg_c;
      float Pn2 = lg2add(Pn, pf_c) + xn;
      float Pb2 = lg2add(Pn, Pb) + xb_c;
      Pn = Pn2; Pb = Pb2;
      float vv = (t < xlb) ? lg2add(Pn, Pb) : LOG2ZERO;   // off critical path
      float nm = fmaxf(mrun, vv);
      srun = srun * fexp2(mrun - nm) + fexp2(vv - nm);
      mrun = nm;
      sl_c = sl_n; lg_c = lg_n; xb_c = xb_n; pf_c = pf_n;
    }
    {   // peeled final iteration t = Tt-1
      const int t = Tt - 1;
      float xn = sl_c - lg_c;
      float Pn2 = lg2add(Pn, pf_c) + xn;
      float Pb2 = lg2add(Pn, Pb) + xb_c;
      Pn = Pn2; Pb = Pb2;
      float vv = (t < xlb) ? lg2add(Pn, Pb) : LOG2ZERO;
      float nm = fmaxf(mrun, vv);
      srun = srun * fexp2(mrun - nm) + fexp2(vv - nm);
      mrun = nm;
    }
    curP = (mrun + flog2(srun)) * LN2;       // back to ln domain
  }
  __syncthreads();   // LOGZERO fill + lastP1 complete

  if (tid < 64) {
    if (tid < CB) orow[beam[b * CB + tid]] = curP;
  }
  __syncthreads();
  if (tid == 0) {
    float eosv = (xlb >= 1) ? lastP1[xlb - 1] * LN2 : 0.0f;
    orow[*eosp] = eosv;
    orow[*blankp] = LOGZERO;
  }
}

extern "C" void kernel_launch(void* const* d_in, const int* in_sizes, int n_in,
                              void* d_out, int out_size, void* d_ws, size_t ws_size,
                              hipStream_t stream) {
  (void)n_in; (void)out_size; (void)ws_size;
  const float* x    = (const float*)d_in[0];
  const float* W    = (const float*)d_in[1];
  const float* bias = (const float*)d_in[2];
  const int* xl     = (const int*)d_in[3];
  const int* beam   = (const int*)d_in[5];
  const int* blankp = (const int*)d_in[6];
  const int* eosp   = (const int*)d_in[7];
  const int Ly = in_sizes[4] / Bb;
  const int CB = in_sizes[5] / Bb;

  float* Spart = (float*)d_ws;                                            // 1 MB
  float* selL  = (float*)((char*)d_ws + (size_t)0x100000);                // 2.03 MB
  unsigned char* Xfp = (unsigned char*)((char*)d_ws + (size_t)0x400000);  // 8 MB
  unsigned char* Wp  = (unsigned char*)((char*)d_ws + (size_t)0xC00000);  // 2 MB
  float* outf = (float*)d_out;

  kPre<<<640, 256, 0, stream>>>(x, W, Xfp, Wp);
  kA<<<4096, 256, 0, stream>>>(Xfp, Wp, bias, beam, blankp, Spart, selL, CB);
  kC<<<Bb, 256, 0, stream>>>(selL, Spart, xl, beam, blankp, eosp, outf, Ly, CB);
}